// Round 15
// baseline (462.273 us; speedup 1.0000x reference)
//
#include <hip/hip_runtime.h>
#include <hip/hip_bf16.h>

typedef unsigned short u16;
typedef __bf16 bf16x8 __attribute__((ext_vector_type(8)));
typedef float f32x4 __attribute__((ext_vector_type(4)));
typedef unsigned short u16x8 __attribute__((ext_vector_type(8)));
typedef unsigned long long u64;

#define NB 32      // batch
#define NT 16      // time
#define NN 1000    // nodes
#define NC 16      // in feat
#define NG 32      // gcn out feat
#define NH 512     // hidden
#define NK 32000   // N*G
#define BH (NB*NH) // 16384
#define LWG 64     // lstm workgroups
#define LTH 384    // lstm threads (6 waves)
#define NSPLIT 8   // gemm split-K

__device__ __forceinline__ u16 f2bf(float f) {
    unsigned int u = __float_as_uint(f);
    unsigned int r = u + 0x7FFFu + ((u >> 16) & 1u);
    return (u16)(r >> 16);
}

__device__ __forceinline__ unsigned cvt2(float a, float b) {
    unsigned r;
    asm("v_cvt_pk_bf16_f32 %0, %1, %2" : "=v"(r) : "v"(a), "v"(b));
    return r;
}

__device__ __forceinline__ float sigmoidf(float x) { return 1.f / (1.f + __expf(-x)); }

__device__ __forceinline__ float dot4(float4 a, float4 b) {
    return a.x * b.x + a.y * b.y + a.z * b.z + a.w * b.w;
}

#define AT_LOAD(p)    __hip_atomic_load((p), __ATOMIC_RELAXED, __HIP_MEMORY_SCOPE_AGENT)
#define AT_STORE(p,v) __hip_atomic_store((p), (v), __ATOMIC_RELAXED, __HIP_MEMORY_SCOPE_AGENT)

#define GLOAD16(g, l) __builtin_amdgcn_global_load_lds( \
    (const __attribute__((address_space(1))) void*)(g),  \
    (__attribute__((address_space(3))) void*)(l), 16, 0, 0)

// ---------------- graph prep: deg, norm, CSR by dst (parallel scan) ----------------
__global__ void graph_prep(const int* __restrict__ ei, const float* __restrict__ ew, int E,
                           int* __restrict__ rowptr, int* __restrict__ csr_src,
                           float* __restrict__ csr_nrm) {
    __shared__ float degs[NN];
    __shared__ float dinv[NN];
    __shared__ int cnt[NN];
    __shared__ int rp[NN + 1];
    __shared__ int wsum[16];
    int tid = threadIdx.x, lane = tid & 63, wid = tid >> 6;
    for (int n = tid; n < NN; n += 1024) { degs[n] = 0.f; cnt[n] = 0; }
    __syncthreads();
    for (int e = tid; e < E; e += 1024) {
        int d = ei[E + e];
        atomicAdd(&degs[d], ew[e]);
        atomicAdd(&cnt[d], 1);
    }
    __syncthreads();
    for (int n = tid; n < NN; n += 1024) {
        float d = degs[n];
        dinv[n] = d > 0.f ? rsqrtf(fmaxf(d, 1e-12f)) : 0.f;
    }
    int v = (tid < NN) ? cnt[tid] : 0;
    int inc = v;
#pragma unroll
    for (int d = 1; d < 64; d <<= 1) {
        int u = __shfl_up(inc, d, 64);
        if (lane >= d) inc += u;
    }
    if (lane == 63) wsum[wid] = inc;
    __syncthreads();
    if (tid == 0) {
        int a = 0;
#pragma unroll
        for (int i = 0; i < 16; ++i) { int t = wsum[i]; wsum[i] = a; a += t; }
    }
    __syncthreads();
    int excl = inc - v + wsum[wid];
    if (tid <= NN) { rp[tid] = excl; rowptr[tid] = excl; }
    if (tid < NN) cnt[tid] = 0;
    __syncthreads();
    for (int e = tid; e < E; e += 1024) {
        int d = ei[E + e], s = ei[e];
        int pos = rp[d] + atomicAdd(&cnt[d], 1);
        csr_src[pos] = s;
        csr_nrm[pos] = dinv[s] * ew[e] * dinv[d];
    }
}

// ---------------- fused GCN: xw in LDS, gather from LDS, relu -> bf16 seq ----------------
__global__ __launch_bounds__(1024) void gcn_fused(const float* __restrict__ x,
                                                  const float* __restrict__ gw,
                                                  const float* __restrict__ gb,
                                                  const int* __restrict__ rowptr,
                                                  const int* __restrict__ csr_src,
                                                  const float* __restrict__ csr_nrm,
                                                  u16* __restrict__ seq) {
    __shared__ float xwlds[NN * NG];     // 128 KB
    __shared__ float wlds[NC * NG];      // 2 KB
    __shared__ int rplds[NN + 1];        // 4 KB
    int bt = blockIdx.x;
    int t = bt & 15;
    int tid = threadIdx.x;
    int g = tid & 31, grp = tid >> 5;    // 32 groups of 32 lanes

    for (int i = tid; i < NC * NG; i += 1024) wlds[i] = gw[t * NC * NG + i];
    for (int i = tid; i <= NN; i += 1024) rplds[i] = rowptr[i];
    __syncthreads();

    const float* xbt = x + (size_t)bt * NN * NC;
    for (int r = grp; r < NN; r += 32) {
        const float4* xr = (const float4*)(xbt + r * NC);
        float4 a0 = xr[0], a1 = xr[1], a2 = xr[2], a3 = xr[3];
        float acc = a0.x * wlds[g]        + a0.y * wlds[32 + g]
                  + a0.z * wlds[64 + g]   + a0.w * wlds[96 + g]
                  + a1.x * wlds[128 + g]  + a1.y * wlds[160 + g]
                  + a1.z * wlds[192 + g]  + a1.w * wlds[224 + g]
                  + a2.x * wlds[256 + g]  + a2.y * wlds[288 + g]
                  + a2.z * wlds[320 + g]  + a2.w * wlds[352 + g]
                  + a3.x * wlds[384 + g]  + a3.y * wlds[416 + g]
                  + a3.z * wlds[448 + g]  + a3.w * wlds[480 + g];
        xwlds[r * NG + g] = acc;
    }
    __syncthreads();

    float bias = gb[t * NG + g];
    u16* seqbt = seq + (size_t)bt * NK;
    for (int n = grp; n < NN; n += 32) {
        int p0 = rplds[n], p1 = rplds[n + 1];
        float acc = 0.f;
        for (int p = p0; p < p1; ++p)
            acc += csr_nrm[p] * xwlds[csr_src[p] * NG + g];
        seqbt[n * NG + g] = f2bf(fmaxf(acc + bias, 0.f));
    }
}

// ---------------- big GEMM: part[s] += seq(512xK bf16) @ w_ih0(2048xK fp32)^T ----------------
// R10 pipeline (dbuf + XOR swizzle + counted vmcnt + 2-deep B prefetch) re-parameterized
// for occupancy: 512 thr / 8 waves, per-wave 32x64 output (acc 2x4 = 32 AGPR), B stage
// 4 float4/set (32 VGPR), A via gload_lds (2 DMAs/tile). ~90-100 regs -> 4 waves/SIMD,
// LDS 64KB -> 2 blocks/CU = 16 waves/CU. vmcnt(4) drains A DMAs, keeps 4 B in flight.
__global__ __launch_bounds__(512, 4) void gemm_hi(const u16* __restrict__ A,
                                                  const float* __restrict__ Bw,
                                                  float* __restrict__ part) {
    __shared__ __align__(16) u16 As[2][128 * 64];   // 16 KB each
    __shared__ __align__(16) u16 Bs[2][128 * 64];
    int tid = threadIdx.x;
    int lane = tid & 63, wid = tid >> 6;
    int wr = wid >> 1, wc = wid & 1;     // wave -> 32-row stripe x 64-col half
    int bid = blockIdx.x;
    int s = bid & 7;
    int idx = bid >> 3;
    int tm = (idx & 3) * 128, tn = (idx >> 2) * 128;
    int ks0 = s * 62 + (s < 4 ? s : 4);
    int ksn = (s < 4) ? 63 : 62;

    // A staging: thread -> row sr (0..63), chunk sc; +64 rows on 2nd DMA.
    int sr = tid >> 3, sc = tid & 7;
    int sce = sc ^ (sr & 7);             // pre-swizzled source chunk
    int sce2 = sc ^ ((sr + 64) & 7);
    const u16* gaBase  = A + (size_t)(tm + sr) * NK + (size_t)ks0 * 64 + sce * 8;
    const u16* gaBase2 = A + (size_t)(tm + 64 + sr) * NK + (size_t)ks0 * 64 + sce2 * 8;
    // B staging: thread -> row br (0..127), quarter bq (chunks 2bq, 2bq+1), src-swizzled
    int br = tid >> 2, bq = tid & 3;
    int ce0 = (2 * bq) ^ (br & 7), ce1 = (2 * bq + 1) ^ (br & 7);
    const float* gB0 = Bw + (size_t)(tn + br) * NK + (size_t)ks0 * 64 + ce0 * 8;
    const float* gB1 = Bw + (size_t)(tn + br) * NK + (size_t)ks0 * 64 + ce1 * 8;

    f32x4 acc[2][4];
#pragma unroll
    for (int i = 0; i < 2; ++i)
#pragma unroll
        for (int j = 0; j < 4; ++j) acc[i][j] = (f32x4){0.f, 0.f, 0.f, 0.f};

    int fr = lane & 15, kq = lane >> 4, fs = fr & 7;

    float4 bqA[4], bqB[4];   // two named B-prefetch sets (static indexing only)

    auto issueA = [&](int kt, int buf) {
        GLOAD16(gaBase  + (size_t)kt * 64, &As[buf][0] + sr * 64 + sc * 8);
        GLOAD16(gaBase2 + (size_t)kt * 64, &As[buf][0] + (64 + sr) * 64 + sc * 8);
    };
    auto loadB = [&](int kt, float4* dst) {
        size_t o = (size_t)kt * 64;
        dst[0] = *(const float4*)(gB0 + o);
        dst[1] = *(const float4*)(gB0 + o + 4);
        dst[2] = *(const float4*)(gB1 + o);
        dst[3] = *(const float4*)(gB1 + o + 4);
    };
    auto cvtB = [&](const float4* src, int buf) {
        uint4 w;
        w.x = cvt2(src[0].x, src[0].y); w.y = cvt2(src[0].z, src[0].w);
        w.z = cvt2(src[1].x, src[1].y); w.w = cvt2(src[1].z, src[1].w);
        *(uint4*)(&Bs[buf][0] + br * 64 + (2 * bq) * 8) = w;
        w.x = cvt2(src[2].x, src[2].y); w.y = cvt2(src[2].z, src[2].w);
        w.z = cvt2(src[3].x, src[3].y); w.w = cvt2(src[3].z, src[3].w);
        *(uint4*)(&Bs[buf][0] + br * 64 + (2 * bq + 1) * 8) = w;
    };
    auto mfmaStep = [&](int buf) {
        const u16* Ap = &As[buf][0];
        const u16* Bp = &Bs[buf][0];
#pragma unroll
        for (int kk = 0; kk < 2; ++kk) {
            int c0 = ((kq + kk * 4) ^ fs) * 8;
            bf16x8 af[2], bv[4];
#pragma unroll
            for (int fm = 0; fm < 2; ++fm)
                af[fm] = *(const bf16x8*)(Ap + (wr * 32 + fm * 16 + fr) * 64 + c0);
#pragma unroll
            for (int fn = 0; fn < 4; ++fn)
                bv[fn] = *(const bf16x8*)(Bp + (wc * 64 + fn * 16 + fr) * 64 + c0);
#pragma unroll
            for (int fm = 0; fm < 2; ++fm)
#pragma unroll
                for (int fn = 0; fn < 4; ++fn)
                    acc[fm][fn] = __builtin_amdgcn_mfma_f32_16x16x32_bf16(af[fm], bv[fn], acc[fm][fn], 0, 0, 0);
        }
    };

    // ---- prologue ----
    issueA(0, 0);                 // [2 outstanding]
    loadB(0, bqA);                // [6]
    loadB(ksn > 1 ? 1 : 0, bqB);  // [10]
    cvtB(bqA, 0);                 // waits bqA -> also drains A(0)
    asm volatile("s_waitcnt lgkmcnt(0)" ::: "memory");
    asm volatile("s_barrier" ::: "memory");
    // steady state top-of-iter: outstanding = B(ks+1)[4]

#define STEP(KS, P, CUR, NXT)                                                  \
    {                                                                          \
        int kA = (KS) + 1 < ksn ? (KS) + 1 : ksn - 1;                          \
        int kB = (KS) + 2 < ksn ? (KS) + 2 : ksn - 1;                          \
        issueA(kA, (P) ^ 1);              /* +2 */                             \
        loadB(kB, NXT);                   /* +4 */                             \
        mfmaStep(P);                                                           \
        cvtB(CUR, (P) ^ 1);               /* waits CUR landed */               \
        asm volatile("s_waitcnt vmcnt(4) lgkmcnt(0)" ::: "memory");            \
        asm volatile("s_barrier" ::: "memory");                                \
    }

    int ks = 0;
    while (ks + 2 <= ksn) {
        STEP(ks, 0, bqB, bqA);
        STEP(ks + 1, 1, bqA, bqB);
        ks += 2;
    }
    if (ks < ksn) {   // odd tail
        STEP(ks, 0, bqB, bqA);
    }
#undef STEP

    int rq = lane >> 4;
    size_t base = (size_t)s * 512 * 2048;
#pragma unroll
    for (int fm = 0; fm < 2; ++fm)
#pragma unroll
        for (int fn = 0; fn < 4; ++fn)
#pragma unroll
            for (int rr = 0; rr < 4; ++rr) {
                int m = tm + wr * 32 + fm * 16 + rq * 4 + rr;
                int n = tn + wc * 64 + fn * 16 + (lane & 15);
                __builtin_nontemporal_store(acc[fm][fn][rr],
                                            &part[base + (size_t)m * 2048 + n]);
            }
}

// ---------------- reduce split-K partials + biases -> pre0p[s][row][b] ----------------
__global__ __launch_bounds__(256) void reduce_bias_p(const float* __restrict__ part,
                                                     const float* __restrict__ b_ih0,
                                                     const float* __restrict__ b_hh0,
                                                     float* __restrict__ pre0p) {
    int s = blockIdx.y;
    int r = blockIdx.x * 64 + (threadIdx.x & 63);
    int bq = threadIdx.x >> 6;  // 0..3
    float bias = b_ih0[r] + b_hh0[r];
#pragma unroll
    for (int b8 = 0; b8 < 8; ++b8) {
        int b = bq * 8 + b8;
        float acc = bias;
#pragma unroll
        for (int sk = 0; sk < NSPLIT; ++sk)
            acc += __builtin_nontemporal_load(
                &part[(size_t)sk * 1048576 + (size_t)(b * 16 + s) * 2048 + r]);
        pre0p[((size_t)s * 2048 + r) * 32 + b] = acc;
    }
}

// ---------------- weight permute: frag-blocked bf16 Wbig[wg][rt][kt][lane][8] ----------------
__global__ __launch_bounds__(256) void wperm(const float* __restrict__ w_hh0,
                                             const float* __restrict__ w_ih1,
                                             const float* __restrict__ w_hh1,
                                             u16* __restrict__ Wbig) {
    int rt = blockIdx.x;   // 0..5
    int wg = blockIdx.y;   // 0..63
    int tid = threadIdx.x;
#pragma unroll
    for (int it = 0; it < 4; ++it) {
        int idx = it * 256 + tid;           // 0..1023
        int kt = idx >> 6, lane = idx & 63;
        int p = rt * 16 + (lane & 15);
        int gate = (p & 31) >> 3;
        int col = wg * 8 + (p & 7);
        const float* src;
        if (p < 32)      src = w_hh0 + (size_t)(gate * NH + col) * NH;
        else if (p < 64) src = w_ih1 + (size_t)(gate * NH + col) * NH;
        else             src = w_hh1 + (size_t)(gate * NH + col) * NH;
        int k0 = kt * 32 + (lane >> 4) * 8;
        float4 v0 = *(const float4*)(src + k0);
        float4 v1 = *(const float4*)(src + k0 + 4);
        u16x8 o;
        o[0] = f2bf(v0.x); o[1] = f2bf(v0.y); o[2] = f2bf(v0.z); o[3] = f2bf(v0.w);
        o[4] = f2bf(v1.x); o[5] = f2bf(v1.y); o[6] = f2bf(v1.z); o[7] = f2bf(v1.w);
        *(u16x8*)(Wbig + (((size_t)wg * 6 + rt) * 16 + kt) * 512 + lane * 8) = o;
    }
}

__global__ void init2(u16* h0, u16* h1, int* flags) {
    int i = blockIdx.x * 256 + threadIdx.x;
    if (i < 2 * BH) { h0[i] = 0; h1[i] = 0; }
    if (i < 1024) flags[i] = 0;
}

// ---------------- persistent MFMA LSTM: 64 WGs x 384 thr ----------------
__global__ __launch_bounds__(LTH) void lstm2(const u16* __restrict__ Wbig,
                                             const float* __restrict__ pre0p,
                                             const float* __restrict__ b_ih1,
                                             const float* __restrict__ b_hh1,
                                             u16* __restrict__ h0buf,   // 2*BH bf16
                                             u16* __restrict__ h1buf,   // 2*BH bf16
                                             float* __restrict__ h1f,   // BH fp32 (final)
                                             int* __restrict__ flags) {
    __shared__ __align__(16) u16 hA0[32 * 520];    // 33.3 KB, 1040B rows
    __shared__ __align__(16) u16 hA1[32 * 520];
    __shared__ float G[96][33];                    // gate outputs, padded
    __shared__ float cst[2][8][32];                // c-state [layer][col][b]
    __shared__ u16 hst[2][8][32];                  // h bf16 staging
    int wg = blockIdx.x, tid = threadIdx.x;
    int wid = tid >> 6, lane = tid & 63;
    int grp = wid >> 1;

    // A-frags into registers (coalesced, once)
    bf16x8 af[16];
    const u16* wsrc = Wbig + (size_t)wg * 49152 + wid * 8192 + lane * 8;
#pragma unroll
    for (int kt = 0; kt < 16; ++kt) af[kt] = *(const bf16x8*)(wsrc + kt * 512);

    if (tid < 512) ((float*)cst)[tid] = 0.f;

    // update-thread constants
    int uj = (tid >> 5) & 7, ub = tid & 31;
    int ucol = wg * 8 + uj;
    float bs0 = 0.f, bs1 = 0.f, bs2 = 0.f, bs3 = 0.f;
    if (tid < 256) {
        bs0 = b_ih1[ucol] + b_hh1[ucol];
        bs1 = b_ih1[NH + ucol] + b_hh1[NH + ucol];
        bs2 = b_ih1[2 * NH + ucol] + b_hh1[2 * NH + ucol];
        bs3 = b_ih1[3 * NH + ucol] + b_hh1[3 * NH + ucol];
    }
    __syncthreads();

    for (int s = 0; s <= 16; ++s) {
        // ---- cooperative coherent stage: h0prev -> hA0, h1prev -> hA1 ----
        for (int r = wid; r < 64; r += 6) {
            const u64* src = (r < 32)
                ? (const u64*)(h0buf + ((s & 1) ^ 1) * BH + r * 512)
                : (const u64*)(h1buf + (s & 1) * BH + (r - 32) * 512);
            u16* dst = (r < 32) ? (hA0 + r * 520) : (hA1 + (r - 32) * 520);
            u64 v0 = AT_LOAD(src + lane);
            u64 v1 = AT_LOAD(src + 64 + lane);
            *(u64*)(dst + lane * 4) = v0;
            *(u64*)(dst + 256 + lane * 4) = v1;
        }
        // prefetch pre0p for this step (plain cached loads)
        float up0 = 0.f, up1 = 0.f, up2 = 0.f, up3 = 0.f;
        if (tid < 256 && s < 16) {
            const float* pp = pre0p + (size_t)s * 2048 * 32 + ub;
            up0 = pp[(size_t)ucol * 32];
            up1 = pp[((size_t)NH + ucol) * 32];
            up2 = pp[((size_t)2 * NH + ucol) * 32];
            up3 = pp[((size_t)3 * NH + ucol) * 32];
        }
        __syncthreads();   // stage complete

        // ---- MFMA: A from registers, B from LDS ----
        bool active = (grp == 0) ? (s < 16) : (s >= 1);
        if (active) {
            const u16* hA = (grp < 2) ? hA0 : hA1;
            const u16* hp = hA + (lane & 15) * 520 + (lane >> 4) * 8;
            f32x4 a0 = (f32x4){0.f, 0.f, 0.f, 0.f};
            f32x4 a1 = (f32x4){0.f, 0.f, 0.f, 0.f};
#pragma unroll
            for (int kt = 0; kt < 16; ++kt) {
                bf16x8 b0 = *(const bf16x8*)(hp + kt * 32);
                bf16x8 b1 = *(const bf16x8*)(hp + 16 * 520 + kt * 32);
                a0 = __builtin_amdgcn_mfma_f32_16x16x32_bf16(af[kt], b0, a0, 0, 0, 0);
                a1 = __builtin_amdgcn_mfma_f32_16x16x32_bf16(af[kt], b1, a1, 0, 0, 0);
            }
            int r0 = wid * 16 + (lane >> 4) * 4;
#pragma unroll
            for (int rr = 0; rr < 4; ++rr) {
                G[r0 + rr][lane & 15] = a0[rr];
                G[r0 + rr][16 + (lane & 15)] = a1[rr];
            }
        }
        __syncthreads();

        // ---- gate updates ----
        if (tid < 256) {
            if (s < 16) {  // layer 0
                float gi = G[uj][ub] + up0;
                float gf = G[8 + uj][ub] + up1;
                float gg = G[16 + uj][ub] + up2;
                float go = G[24 + uj][ub] + up3;
                float c = sigmoidf(gf) * cst[0][uj][ub] + sigmoidf(gi) * tanhf(gg);
                cst[0][uj][ub] = c;
                hst[0][uj][ub] = f2bf(sigmoidf(go) * tanhf(c));
            }
            if (s >= 1) {  // layer 1 (t = s-1)
                float gi = G[32 + uj][ub] + G[64 + uj][ub] + bs0;
                float gf = G[40 + uj][ub] + G[72 + uj][ub] + bs1;
                float gg = G[48 + uj][ub] + G[80 + uj][ub] + bs2;
                float go = G[56 + uj][ub] + G[88 + uj][ub] + bs3;
                float c = sigmoidf(gf) * cst[1][uj][ub] + sigmoidf(gi) * tanhf(gg);
                cst[1][uj][ub] = c;
                float hv = sigmoidf(go) * tanhf(c);
                hst[1][uj][ub] = f2bf(hv);
                if (s == 16) h1f[ub * NH + ucol] = hv;
            }
        }
        __syncthreads();

        // ---- publish (write-through atomics) + flag barrier, no fences ----
        if (s < 16) {
            if (wid == 0) {
                if (lane < 32) {
                    union { u16 a[8]; u64 q[2]; } v;
#pragma unroll
                    for (int j = 0; j < 8; ++j) v.a[j] = hst[0][j][lane];
                    u64* d = (u64*)(h0buf + (s & 1) * BH + lane * 512 + wg * 8);
                    AT_STORE(d, v.q[0]); AT_STORE(d + 1, v.q[1]);
                } else if (s >= 1) {
                    int b = lane - 32;
                    union { u16 a[8]; u64 q[2]; } v;
#pragma unroll
                    for (int j = 0; j < 8; ++j) v.a[j] = hst[1][j][b];
                    u64* d = (u64*)(h1buf + ((s - 1) & 1) * BH + b * 512 + wg * 8);
                    AT_STORE(d, v.q[0]); AT_STORE(d + 1, v.q[1]);
                }
                asm volatile("s_waitcnt vmcnt(0)" ::: "memory");
                if (lane == 0) AT_STORE(&flags[wg * 16], s + 1);
                int target = s + 1;
                for (;;) {
                    int v = AT_LOAD(&flags[lane * 16]);
                    if (__all(v >= target)) break;
                    __builtin_amdgcn_s_sleep(1);
                }
            }
            __syncthreads();
        }
    }
}

// ---------------- projection from fp32 final h1 ----------------
__global__ __launch_bounds__(1024) void proj_k(const float* __restrict__ h1f,
                                               const float* __restrict__ proj_w,
                                               const float* __restrict__ proj_b,
                                               float* __restrict__ out) {
    __shared__ float pj[32][8][4];
    int tid = threadIdx.x;
    int b = tid >> 5, o = (tid >> 2) & 7, kq = tid & 3;
    const float4* hp = (const float4*)(h1f + (size_t)b * NH + kq * 128);
    const float4* wp = (const float4*)(proj_w + (size_t)o * NH + kq * 128);
    float acc = 0.f;
#pragma unroll 8
    for (int k = 0; k < 32; ++k) acc += dot4(hp[k], wp[k]);
    pj[b][o][kq] = acc;
    __syncthreads();
    if (tid < 256) {
        int bb = tid >> 3, oo = tid & 7;
        out[bb * 8 + oo] = pj[bb][oo][0] + pj[bb][oo][1] + pj[bb][oo][2] + pj[bb][oo][3] + proj_b[oo];
    }
}

extern "C" void kernel_launch(void* const* d_in, const int* in_sizes, int n_in,
                              void* d_out, int out_size, void* d_ws, size_t ws_size,
                              hipStream_t stream) {
    const float* x      = (const float*)d_in[0];
    const int*   ei     = (const int*)d_in[1];
    const float* ew     = (const float*)d_in[2];
    const float* gcn_w  = (const float*)d_in[3];
    const float* gcn_b  = (const float*)d_in[4];
    const float* w_ih0  = (const float*)d_in[5];
    const float* w_hh0  = (const float*)d_in[6];
    const float* b_ih0  = (const float*)d_in[7];
    const float* b_hh0  = (const float*)d_in[8];
    const float* w_ih1  = (const float*)d_in[9];
    const float* w_hh1  = (const float*)d_in[10];
    const float* b_ih1  = (const float*)d_in[11];
    const float* b_hh1  = (const float*)d_in[12];
    const float* proj_w = (const float*)d_in[13];
    const float* proj_b = (const float*)d_in[14];
    int E = in_sizes[2];

    char* ws = (char*)d_ws;
    size_t off = 0;
    float* part   = (float*)(ws + off);                          // NSPLIT*512*2048 f32 (33.5MB)
    u16* Wbig     = (u16*)part;        off += 50331648;          // aliases part (6.3MB, after reduce)
    u16* seq      = (u16*)(ws + off);  off += 32768000;          // 512*32000 bf16
    float* pre0p  = (float*)(ws + off); off += 4194304;          // [16][2048][32] f32
    u16* h0buf    = (u16*)(ws + off);  off += 2 * BH * 2;
    u16* h1buf    = (u16*)(ws + off);  off += 2 * BH * 2;
    float* h1f    = (float*)(ws + off); off += BH * 4;
    int* flags    = (int*)(ws + off);  off += 4096;
    int* rowptr   = (int*)(ws + off);  off += 4096;
    int* csr_src  = (int*)(ws + off);  off += 36864;
    float* csr_nrm = (float*)(ws + off); off += 36864;
    (void)ws_size; (void)n_in; (void)out_size;

    graph_prep<<<1, 1024, 0, stream>>>(ei, ew, E, rowptr, csr_src, csr_nrm);
    gcn_fused<<<512, 1024, 0, stream>>>(x, gcn_w, gcn_b, rowptr, csr_src, csr_nrm, seq);
    gemm_hi<<<512, 512, 0, stream>>>(seq, w_ih0, part);
    reduce_bias_p<<<dim3(32, 16), 256, 0, stream>>>(part, b_ih0, b_hh0, pre0p);
    // part is now consumed -> its region hosts Wbig
    wperm<<<dim3(6, 64), 256, 0, stream>>>(w_hh0, w_ih1, w_hh1, Wbig);
    init2<<<128, 256, 0, stream>>>(h0buf, h1buf, flags);

    lstm2<<<LWG, LTH, 0, stream>>>(Wbig, pre0p, b_ih1, b_hh1, h0buf, h1buf, h1f, flags);
    proj_k<<<1, 1024, 0, stream>>>(h1f, proj_w, proj_b, (float*)d_out);
}

// Round 16
// 443.765 us; speedup vs baseline: 1.0417x; 1.0417x over previous
//
#include <hip/hip_runtime.h>
#include <hip/hip_bf16.h>

typedef unsigned short u16;
typedef __bf16 bf16x8 __attribute__((ext_vector_type(8)));
typedef float f32x4 __attribute__((ext_vector_type(4)));
typedef unsigned short u16x8 __attribute__((ext_vector_type(8)));
typedef unsigned long long u64;

#define NB 32      // batch
#define NT 16      // time
#define NN 1000    // nodes
#define NC 16      // in feat
#define NG 32      // gcn out feat
#define NH 512     // hidden
#define NK 32000   // N*G
#define BH (NB*NH) // 16384
#define LWG 64     // lstm workgroups
#define LTH 384    // lstm threads (6 waves)
#define NSPLIT 8   // gemm split-K

__device__ __forceinline__ u16 f2bf(float f) {
    unsigned int u = __float_as_uint(f);
    unsigned int r = u + 0x7FFFu + ((u >> 16) & 1u);
    return (u16)(r >> 16);
}

__device__ __forceinline__ unsigned cvt2(float a, float b) {
    unsigned r;
    asm("v_cvt_pk_bf16_f32 %0, %1, %2" : "=v"(r) : "v"(a), "v"(b));
    return r;
}

__device__ __forceinline__ float sigmoidf(float x) { return 1.f / (1.f + __expf(-x)); }

__device__ __forceinline__ float dot4(float4 a, float4 b) {
    return a.x * b.x + a.y * b.y + a.z * b.z + a.w * b.w;
}

#define AT_LOAD(p)    __hip_atomic_load((p), __ATOMIC_RELAXED, __HIP_MEMORY_SCOPE_AGENT)
#define AT_STORE(p,v) __hip_atomic_store((p), (v), __ATOMIC_RELAXED, __HIP_MEMORY_SCOPE_AGENT)

#define GLOAD16(g, l) __builtin_amdgcn_global_load_lds( \
    (const __attribute__((address_space(1))) void*)(g),  \
    (__attribute__((address_space(3))) void*)(l), 16, 0, 0)

// ---------------- graph prep: deg, norm, CSR by dst (parallel scan) ----------------
__global__ void graph_prep(const int* __restrict__ ei, const float* __restrict__ ew, int E,
                           int* __restrict__ rowptr, int* __restrict__ csr_src,
                           float* __restrict__ csr_nrm) {
    __shared__ float degs[NN];
    __shared__ float dinv[NN];
    __shared__ int cnt[NN];
    __shared__ int rp[NN + 1];
    __shared__ int wsum[16];
    int tid = threadIdx.x, lane = tid & 63, wid = tid >> 6;
    for (int n = tid; n < NN; n += 1024) { degs[n] = 0.f; cnt[n] = 0; }
    __syncthreads();
    for (int e = tid; e < E; e += 1024) {
        int d = ei[E + e];
        atomicAdd(&degs[d], ew[e]);
        atomicAdd(&cnt[d], 1);
    }
    __syncthreads();
    for (int n = tid; n < NN; n += 1024) {
        float d = degs[n];
        dinv[n] = d > 0.f ? rsqrtf(fmaxf(d, 1e-12f)) : 0.f;
    }
    int v = (tid < NN) ? cnt[tid] : 0;
    int inc = v;
#pragma unroll
    for (int d = 1; d < 64; d <<= 1) {
        int u = __shfl_up(inc, d, 64);
        if (lane >= d) inc += u;
    }
    if (lane == 63) wsum[wid] = inc;
    __syncthreads();
    if (tid == 0) {
        int a = 0;
#pragma unroll
        for (int i = 0; i < 16; ++i) { int t = wsum[i]; wsum[i] = a; a += t; }
    }
    __syncthreads();
    int excl = inc - v + wsum[wid];
    if (tid <= NN) { rp[tid] = excl; rowptr[tid] = excl; }
    if (tid < NN) cnt[tid] = 0;
    __syncthreads();
    for (int e = tid; e < E; e += 1024) {
        int d = ei[E + e], s = ei[e];
        int pos = rp[d] + atomicAdd(&cnt[d], 1);
        csr_src[pos] = s;
        csr_nrm[pos] = dinv[s] * ew[e] * dinv[d];
    }
}

// ---------------- fused GCN: xw in LDS, gather from LDS, relu -> bf16 seq ----------------
__global__ __launch_bounds__(1024) void gcn_fused(const float* __restrict__ x,
                                                  const float* __restrict__ gw,
                                                  const float* __restrict__ gb,
                                                  const int* __restrict__ rowptr,
                                                  const int* __restrict__ csr_src,
                                                  const float* __restrict__ csr_nrm,
                                                  u16* __restrict__ seq) {
    __shared__ float xwlds[NN * NG];     // 128 KB
    __shared__ float wlds[NC * NG];      // 2 KB
    __shared__ int rplds[NN + 1];        // 4 KB
    int bt = blockIdx.x;
    int t = bt & 15;
    int tid = threadIdx.x;
    int g = tid & 31, grp = tid >> 5;    // 32 groups of 32 lanes

    for (int i = tid; i < NC * NG; i += 1024) wlds[i] = gw[t * NC * NG + i];
    for (int i = tid; i <= NN; i += 1024) rplds[i] = rowptr[i];
    __syncthreads();

    const float* xbt = x + (size_t)bt * NN * NC;
    for (int r = grp; r < NN; r += 32) {
        const float4* xr = (const float4*)(xbt + r * NC);
        float4 a0 = xr[0], a1 = xr[1], a2 = xr[2], a3 = xr[3];
        float acc = a0.x * wlds[g]        + a0.y * wlds[32 + g]
                  + a0.z * wlds[64 + g]   + a0.w * wlds[96 + g]
                  + a1.x * wlds[128 + g]  + a1.y * wlds[160 + g]
                  + a1.z * wlds[192 + g]  + a1.w * wlds[224 + g]
                  + a2.x * wlds[256 + g]  + a2.y * wlds[288 + g]
                  + a2.z * wlds[320 + g]  + a2.w * wlds[352 + g]
                  + a3.x * wlds[384 + g]  + a3.y * wlds[416 + g]
                  + a3.z * wlds[448 + g]  + a3.w * wlds[480 + g];
        xwlds[r * NG + g] = acc;
    }
    __syncthreads();

    float bias = gb[t * NG + g];
    u16* seqbt = seq + (size_t)bt * NK;
    for (int n = grp; n < NN; n += 32) {
        int p0 = rplds[n], p1 = rplds[n + 1];
        float acc = 0.f;
        for (int p = p0; p < p1; ++p)
            acc += csr_nrm[p] * xwlds[csr_src[p] * NG + g];
        seqbt[n * NG + g] = f2bf(fmaxf(acc + bias, 0.f));
    }
}

// ---------------- big GEMM: part[s] += seq(512xK bf16) @ w_ih0(2048xK fp32)^T ----------------
// Best-measured (R10/R14): dbuf LDS + XOR swizzle + counted-vmcnt raw barrier + 2-deep B
// register prefetch: B(ks+2) stays in flight ACROSS the barrier (vmcnt(8) drains only the
// 4 A-gloads). Buffer parity compile-time via pair-unrolled loop. nt on part stores.
__global__ __launch_bounds__(256) void gemm_f32b(const u16* __restrict__ A,
                                                 const float* __restrict__ Bw,
                                                 float* __restrict__ part) {
    __shared__ __align__(16) u16 As[2][128 * 64];
    __shared__ __align__(16) u16 Bs[2][128 * 64];
    int tid = threadIdx.x;
    int lane = tid & 63, wid = tid >> 6;
    int wr = wid >> 1, wc = wid & 1;
    int bid = blockIdx.x;
    int s = bid & 7;
    int idx = bid >> 3;
    int tm = (idx & 3) * 128, tn = (idx >> 2) * 128;
    int ks0 = s * 62 + (s < 4 ? s : 4);
    int ksn = (s < 4) ? 63 : 62;

    // A staging: source chunk pre-swizzled (dest linear)
    int srow = tid >> 3, sc = tid & 7;
    int sce = sc ^ (srow & 7);
    const u16* gaBase = A + (size_t)(tm + srow) * NK + (size_t)ks0 * 64 + sce * 8;
    // B staging: physical chunk bc, swizzled source chunk bce
    int br = tid >> 3, bc = tid & 7;
    int bce = bc ^ (br & 7);
    const float* gbBase = Bw + (size_t)(tn + br) * NK + (size_t)ks0 * 64 + bce * 8;

    f32x4 acc[4][4];
#pragma unroll
    for (int i = 0; i < 4; ++i)
#pragma unroll
        for (int j = 0; j < 4; ++j) acc[i][j] = (f32x4){0.f, 0.f, 0.f, 0.f};

    int fr = lane & 15, kq = lane >> 4, fs = fr & 7;

    float4 bqA[8], bqB[8];   // two named B-prefetch sets (static indexing only)

    auto issueA = [&](int kt, int buf) {
#pragma unroll
        for (int q = 0; q < 4; ++q)
            GLOAD16(gaBase + (size_t)kt * 64 + (size_t)q * 32 * NK,
                    &As[buf][0] + srow * 64 + sc * 8 + q * 32 * 64);
    };
    auto loadB = [&](int kt, float4* dst) {
        const float* g = gbBase + (size_t)kt * 64;
#pragma unroll
        for (int q = 0; q < 4; ++q) {
            dst[2 * q]     = *(const float4*)(g + (size_t)q * 32 * NK);
            dst[2 * q + 1] = *(const float4*)(g + (size_t)q * 32 * NK + 4);
        }
    };
    auto cvtB = [&](const float4* src, int buf) {
#pragma unroll
        for (int q = 0; q < 4; ++q) {
            uint4 w;
            w.x = cvt2(src[2 * q].x, src[2 * q].y);
            w.y = cvt2(src[2 * q].z, src[2 * q].w);
            w.z = cvt2(src[2 * q + 1].x, src[2 * q + 1].y);
            w.w = cvt2(src[2 * q + 1].z, src[2 * q + 1].w);
            *(uint4*)(&Bs[buf][0] + (br + q * 32) * 64 + bc * 8) = w;
        }
    };
    auto mfmaStep = [&](int buf) {
        const u16* Ap = &As[buf][0];
        const u16* Bp = &Bs[buf][0];
#pragma unroll
        for (int kk = 0; kk < 2; ++kk) {
            int c0 = ((kq + kk * 4) ^ fs) * 8;
            bf16x8 af[4], bv[4];
#pragma unroll
            for (int fm = 0; fm < 4; ++fm)
                af[fm] = *(const bf16x8*)(Ap + (wr * 64 + fm * 16 + fr) * 64 + c0);
#pragma unroll
            for (int fn = 0; fn < 4; ++fn)
                bv[fn] = *(const bf16x8*)(Bp + (wc * 64 + fn * 16 + fr) * 64 + c0);
#pragma unroll
            for (int fm = 0; fm < 4; ++fm)
#pragma unroll
                for (int fn = 0; fn < 4; ++fn)
                    acc[fm][fn] = __builtin_amdgcn_mfma_f32_16x16x32_bf16(af[fm], bv[fn], acc[fm][fn], 0, 0, 0);
        }
    };

    // ---- prologue ----
    issueA(0, 0);                 // A(0) -> buf0            [4 outstanding]
    loadB(0, bqA);                // B(0) -> bqA             [12]
    loadB(ksn > 1 ? 1 : 0, bqB);  // B(1) -> bqB             [20]
    cvtB(bqA, 0);                 // consumes B(0): waits vmcnt<=12 -> A(0) drained too
    asm volatile("s_waitcnt lgkmcnt(0)" ::: "memory");
    asm volatile("s_barrier" ::: "memory");
    // steady state top-of-iter: outstanding = B(ks+1)[8]

#define STEP(KS, P, CUR, NXT)                                                  \
    {                                                                          \
        int kA = (KS) + 1 < ksn ? (KS) + 1 : ksn - 1;                          \
        int kB = (KS) + 2 < ksn ? (KS) + 2 : ksn - 1;                          \
        issueA(kA, (P) ^ 1);              /* +4  -> CUR[8] + A[4] */           \
        loadB(kB, NXT);                   /* +8  -> CUR[8] + A[4] + NXT[8] */  \
        mfmaStep(P);                                                           \
        cvtB(CUR, (P) ^ 1);               /* waits vmcnt<=12 (CUR done) */     \
        asm volatile("s_waitcnt vmcnt(8) lgkmcnt(0)" ::: "memory");            \
        asm volatile("s_barrier" ::: "memory");                                \
    }

    int ks = 0;
    while (ks + 2 <= ksn) {
        STEP(ks, 0, bqB, bqA);
        STEP(ks + 1, 1, bqA, bqB);
        ks += 2;
    }
    if (ks < ksn) {   // odd tail (ksn odd): one more step on buf 0
        STEP(ks, 0, bqB, bqA);
    }
#undef STEP

    int rq = lane >> 4;
    size_t base = (size_t)s * 512 * 2048;
#pragma unroll
    for (int fm = 0; fm < 4; ++fm)
#pragma unroll
        for (int fn = 0; fn < 4; ++fn)
#pragma unroll
            for (int rr = 0; rr < 4; ++rr) {
                int m = tm + wr * 64 + fm * 16 + rq * 4 + rr;
                int n = tn + wc * 64 + fn * 16 + (lane & 15);
                __builtin_nontemporal_store(acc[fm][fn][rr],
                                            &part[base + (size_t)m * 2048 + n]);
            }
}

// ---------------- reduce split-K partials + biases -> pre0p[s][row][b] ----------------
__global__ __launch_bounds__(256) void reduce_bias_p(const float* __restrict__ part,
                                                     const float* __restrict__ b_ih0,
                                                     const float* __restrict__ b_hh0,
                                                     float* __restrict__ pre0p) {
    int s = blockIdx.y;
    int r = blockIdx.x * 64 + (threadIdx.x & 63);
    int bq = threadIdx.x >> 6;  // 0..3
    float bias = b_ih0[r] + b_hh0[r];
#pragma unroll
    for (int b8 = 0; b8 < 8; ++b8) {
        int b = bq * 8 + b8;
        float acc = bias;
#pragma unroll
        for (int sk = 0; sk < NSPLIT; ++sk)
            acc += __builtin_nontemporal_load(
                &part[(size_t)sk * 1048576 + (size_t)(b * 16 + s) * 2048 + r]);
        pre0p[((size_t)s * 2048 + r) * 32 + b] = acc;
    }
}

// ---------------- weight permute + state init (merged) ----------------
// wperm part: frag-blocked bf16 Wbig[wg][rt][kt][lane][8]. init part: first 128
// flattened blocks also zero h0/h1/flags (saves one launch).
__global__ __launch_bounds__(256) void wperm(const float* __restrict__ w_hh0,
                                             const float* __restrict__ w_ih1,
                                             const float* __restrict__ w_hh1,
                                             u16* __restrict__ Wbig,
                                             u16* __restrict__ h0,
                                             u16* __restrict__ h1,
                                             int* __restrict__ flags) {
    int rt = blockIdx.x;   // 0..5
    int wg = blockIdx.y;   // 0..63
    int tid = threadIdx.x;
    int gb = wg * 6 + rt;  // flattened 0..383
    if (gb < 128) {
        int i = gb * 256 + tid;   // < 32768
        h0[i] = 0; h1[i] = 0;
        if (i < 1024) flags[i] = 0;
    }
#pragma unroll
    for (int it = 0; it < 4; ++it) {
        int idx = it * 256 + tid;           // 0..1023
        int kt = idx >> 6, lane = idx & 63;
        int p = rt * 16 + (lane & 15);
        int gate = (p & 31) >> 3;
        int col = wg * 8 + (p & 7);
        const float* src;
        if (p < 32)      src = w_hh0 + (size_t)(gate * NH + col) * NH;
        else if (p < 64) src = w_ih1 + (size_t)(gate * NH + col) * NH;
        else             src = w_hh1 + (size_t)(gate * NH + col) * NH;
        int k0 = kt * 32 + (lane >> 4) * 8;
        float4 v0 = *(const float4*)(src + k0);
        float4 v1 = *(const float4*)(src + k0 + 4);
        u16x8 o;
        o[0] = f2bf(v0.x); o[1] = f2bf(v0.y); o[2] = f2bf(v0.z); o[3] = f2bf(v0.w);
        o[4] = f2bf(v1.x); o[5] = f2bf(v1.y); o[6] = f2bf(v1.z); o[7] = f2bf(v1.w);
        *(u16x8*)(Wbig + (((size_t)wg * 6 + rt) * 16 + kt) * 512 + lane * 8) = o;
    }
}

// ---------------- persistent MFMA LSTM: 64 WGs x 384 thr ----------------
__global__ __launch_bounds__(LTH) void lstm2(const u16* __restrict__ Wbig,
                                             const float* __restrict__ pre0p,
                                             const float* __restrict__ b_ih1,
                                             const float* __restrict__ b_hh1,
                                             u16* __restrict__ h0buf,   // 2*BH bf16
                                             u16* __restrict__ h1buf,   // 2*BH bf16
                                             float* __restrict__ h1f,   // BH fp32 (final)
                                             int* __restrict__ flags) {
    __shared__ __align__(16) u16 hA0[32 * 520];    // 33.3 KB, 1040B rows
    __shared__ __align__(16) u16 hA1[32 * 520];
    __shared__ float G[96][33];                    // gate outputs, padded
    __shared__ float cst[2][8][32];                // c-state [layer][col][b]
    __shared__ u16 hst[2][8][32];                  // h bf16 staging
    int wg = blockIdx.x, tid = threadIdx.x;
    int wid = tid >> 6, lane = tid & 63;
    int grp = wid >> 1;

    // A-frags into registers (coalesced, once)
    bf16x8 af[16];
    const u16* wsrc = Wbig + (size_t)wg * 49152 + wid * 8192 + lane * 8;
#pragma unroll
    for (int kt = 0; kt < 16; ++kt) af[kt] = *(const bf16x8*)(wsrc + kt * 512);

    if (tid < 512) ((float*)cst)[tid] = 0.f;

    // update-thread constants
    int uj = (tid >> 5) & 7, ub = tid & 31;
    int ucol = wg * 8 + uj;
    float bs0 = 0.f, bs1 = 0.f, bs2 = 0.f, bs3 = 0.f;
    if (tid < 256) {
        bs0 = b_ih1[ucol] + b_hh1[ucol];
        bs1 = b_ih1[NH + ucol] + b_hh1[NH + ucol];
        bs2 = b_ih1[2 * NH + ucol] + b_hh1[2 * NH + ucol];
        bs3 = b_ih1[3 * NH + ucol] + b_hh1[3 * NH + ucol];
    }
    __syncthreads();

    for (int s = 0; s <= 16; ++s) {
        // ---- cooperative coherent stage: h0prev -> hA0, h1prev -> hA1 ----
        for (int r = wid; r < 64; r += 6) {
            const u64* src = (r < 32)
                ? (const u64*)(h0buf + ((s & 1) ^ 1) * BH + r * 512)
                : (const u64*)(h1buf + (s & 1) * BH + (r - 32) * 512);
            u16* dst = (r < 32) ? (hA0 + r * 520) : (hA1 + (r - 32) * 520);
            u64 v0 = AT_LOAD(src + lane);
            u64 v1 = AT_LOAD(src + 64 + lane);
            *(u64*)(dst + lane * 4) = v0;
            *(u64*)(dst + 256 + lane * 4) = v1;
        }
        // prefetch pre0p for this step (plain cached loads)
        float up0 = 0.f, up1 = 0.f, up2 = 0.f, up3 = 0.f;
        if (tid < 256 && s < 16) {
            const float* pp = pre0p + (size_t)s * 2048 * 32 + ub;
            up0 = pp[(size_t)ucol * 32];
            up1 = pp[((size_t)NH + ucol) * 32];
            up2 = pp[((size_t)2 * NH + ucol) * 32];
            up3 = pp[((size_t)3 * NH + ucol) * 32];
        }
        __syncthreads();   // stage complete

        // ---- MFMA: A from registers, B from LDS ----
        bool active = (grp == 0) ? (s < 16) : (s >= 1);
        if (active) {
            const u16* hA = (grp < 2) ? hA0 : hA1;
            const u16* hp = hA + (lane & 15) * 520 + (lane >> 4) * 8;
            f32x4 a0 = (f32x4){0.f, 0.f, 0.f, 0.f};
            f32x4 a1 = (f32x4){0.f, 0.f, 0.f, 0.f};
#pragma unroll
            for (int kt = 0; kt < 16; ++kt) {
                bf16x8 b0 = *(const bf16x8*)(hp + kt * 32);
                bf16x8 b1 = *(const bf16x8*)(hp + 16 * 520 + kt * 32);
                a0 = __builtin_amdgcn_mfma_f32_16x16x32_bf16(af[kt], b0, a0, 0, 0, 0);
                a1 = __builtin_amdgcn_mfma_f32_16x16x32_bf16(af[kt], b1, a1, 0, 0, 0);
            }
            int r0 = wid * 16 + (lane >> 4) * 4;
#pragma unroll
            for (int rr = 0; rr < 4; ++rr) {
                G[r0 + rr][lane & 15] = a0[rr];
                G[r0 + rr][16 + (lane & 15)] = a1[rr];
            }
        }
        __syncthreads();

        // ---- gate updates ----
        if (tid < 256) {
            if (s < 16) {  // layer 0
                float gi = G[uj][ub] + up0;
                float gf = G[8 + uj][ub] + up1;
                float gg = G[16 + uj][ub] + up2;
                float go = G[24 + uj][ub] + up3;
                float c = sigmoidf(gf) * cst[0][uj][ub] + sigmoidf(gi) * tanhf(gg);
                cst[0][uj][ub] = c;
                hst[0][uj][ub] = f2bf(sigmoidf(go) * tanhf(c));
            }
            if (s >= 1) {  // layer 1 (t = s-1)
                float gi = G[32 + uj][ub] + G[64 + uj][ub] + bs0;
                float gf = G[40 + uj][ub] + G[72 + uj][ub] + bs1;
                float gg = G[48 + uj][ub] + G[80 + uj][ub] + bs2;
                float go = G[56 + uj][ub] + G[88 + uj][ub] + bs3;
                float c = sigmoidf(gf) * cst[1][uj][ub] + sigmoidf(gi) * tanhf(gg);
                cst[1][uj][ub] = c;
                float hv = sigmoidf(go) * tanhf(c);
                hst[1][uj][ub] = f2bf(hv);
                if (s == 16) h1f[ub * NH + ucol] = hv;
            }
        }
        __syncthreads();

        // ---- publish (write-through atomics) + flag barrier, no fences ----
        if (s < 16) {
            if (wid == 0) {
                if (lane < 32) {
                    union { u16 a[8]; u64 q[2]; } v;
#pragma unroll
                    for (int j = 0; j < 8; ++j) v.a[j] = hst[0][j][lane];
                    u64* d = (u64*)(h0buf + (s & 1) * BH + lane * 512 + wg * 8);
                    AT_STORE(d, v.q[0]); AT_STORE(d + 1, v.q[1]);
                } else if (s >= 1) {
                    int b = lane - 32;
                    union { u16 a[8]; u64 q[2]; } v;
#pragma unroll
                    for (int j = 0; j < 8; ++j) v.a[j] = hst[1][j][b];
                    u64* d = (u64*)(h1buf + ((s - 1) & 1) * BH + b * 512 + wg * 8);
                    AT_STORE(d, v.q[0]); AT_STORE(d + 1, v.q[1]);
                }
                asm volatile("s_waitcnt vmcnt(0)" ::: "memory");
                if (lane == 0) AT_STORE(&flags[wg * 16], s + 1);
                int target = s + 1;
                for (;;) {
                    int v = AT_LOAD(&flags[lane * 16]);
                    if (__all(v >= target)) break;
                    __builtin_amdgcn_s_sleep(1);
                }
            }
            __syncthreads();
        }
    }
}

// ---------------- projection from fp32 final h1 ----------------
__global__ __launch_bounds__(1024) void proj_k(const float* __restrict__ h1f,
                                               const float* __restrict__ proj_w,
                                               const float* __restrict__ proj_b,
                                               float* __restrict__ out) {
    __shared__ float pj[32][8][4];
    int tid = threadIdx.x;
    int b = tid >> 5, o = (tid >> 2) & 7, kq = tid & 3;
    const float4* hp = (const float4*)(h1f + (size_t)b * NH + kq * 128);
    const float4* wp = (const float4*)(proj_w + (size_t)o * NH + kq * 128);
    float acc = 0.f;
#pragma unroll 8
    for (int k = 0; k < 32; ++k) acc += dot4(hp[k], wp[k]);
    pj[b][o][kq] = acc;
    __syncthreads();
    if (tid < 256) {
        int bb = tid >> 3, oo = tid & 7;
        out[bb * 8 + oo] = pj[bb][oo][0] + pj[bb][oo][1] + pj[bb][oo][2] + pj[bb][oo][3] + proj_b[oo];
    }
}

extern "C" void kernel_launch(void* const* d_in, const int* in_sizes, int n_in,
                              void* d_out, int out_size, void* d_ws, size_t ws_size,
                              hipStream_t stream) {
    const float* x      = (const float*)d_in[0];
    const int*   ei     = (const int*)d_in[1];
    const float* ew     = (const float*)d_in[2];
    const float* gcn_w  = (const float*)d_in[3];
    const float* gcn_b  = (const float*)d_in[4];
    const float* w_ih0  = (const float*)d_in[5];
    const float* w_hh0  = (const float*)d_in[6];
    const float* b_ih0  = (const float*)d_in[7];
    const float* b_hh0  = (const float*)d_in[8];
    const float* w_ih1  = (const float*)d_in[9];
    const float* w_hh1  = (const float*)d_in[10];
    const float* b_ih1  = (const float*)d_in[11];
    const float* b_hh1  = (const float*)d_in[12];
    const float* proj_w = (const float*)d_in[13];
    const float* proj_b = (const float*)d_in[14];
    int E = in_sizes[2];

    char* ws = (char*)d_ws;
    size_t off = 0;
    float* part   = (float*)(ws + off);                          // NSPLIT*512*2048 f32 (33.5MB)
    u16* Wbig     = (u16*)part;        off += 50331648;          // aliases part (6.3MB, after reduce)
    u16* seq      = (u16*)(ws + off);  off += 32768000;          // 512*32000 bf16
    float* pre0p  = (float*)(ws + off); off += 4194304;          // [16][2048][32] f32
    u16* h0buf    = (u16*)(ws + off);  off += 2 * BH * 2;
    u16* h1buf    = (u16*)(ws + off);  off += 2 * BH * 2;
    float* h1f    = (float*)(ws + off); off += BH * 4;
    int* flags    = (int*)(ws + off);  off += 4096;
    int* rowptr   = (int*)(ws + off);  off += 4096;
    int* csr_src  = (int*)(ws + off);  off += 36864;
    float* csr_nrm = (float*)(ws + off); off += 36864;
    (void)ws_size; (void)n_in; (void)out_size;

    graph_prep<<<1, 1024, 0, stream>>>(ei, ew, E, rowptr, csr_src, csr_nrm);
    gcn_fused<<<512, 1024, 0, stream>>>(x, gcn_w, gcn_b, rowptr, csr_src, csr_nrm, seq);
    gemm_f32b<<<512, 256, 0, stream>>>(seq, w_ih0, part);
    reduce_bias_p<<<dim3(32, 16), 256, 0, stream>>>(part, b_ih0, b_hh0, pre0p);
    // part is now consumed -> its region hosts Wbig; wperm also zero-inits states
    wperm<<<dim3(6, 64), 256, 0, stream>>>(w_hh0, w_ih1, w_hh1, Wbig, h0buf, h1buf, flags);

    lstm2<<<LWG, LTH, 0, stream>>>(Wbig, pre0p, b_ih1, b_hh1, h0buf, h1buf, h1f, flags);
    proj_k<<<1, 1024, 0, stream>>>(h1f, proj_w, proj_b, (float*)d_out);
}